// Round 4
// baseline (968.312 us; speedup 1.0000x reference)
//
#include <hip/hip_runtime.h>
#include <stdint.h>

// WeightOnlyInt8Linear: out[t,o] = sum_k x[t,k] * (int8 w[o,k] * scale[o]) + bias[o]
// M=8192, K=4096, N=11008. x fp32, w int8-as-int32 (harness), out fp32.
// Round 3: true fine-grained phase schedule (T3+T4): 256x256 tile, BK=64,
// 8 waves (2x4), LDS split into per-(operand x kk-half) 16 KiB regions,
// 4 phases per K-tile, each phase = ds_read subtile || 1 half-tile stage ->
// barrier -> lgkmcnt(0) -> 16 MFMA (setprio) -> barrier. Counted vmcnt(8)
// only at ph1/ph3 boundaries; prefetch depth 5-6 phases. No vmcnt(0) drain
// in the main loop. XOR swizzle both-sides (0 conflicts verified r1/r2).

#define TOKENS 8192
#define IN_F   4096
#define OUT_F  11008

#define BM 256
#define BN 256
#define BK 64
#define KT   (IN_F / BK)     // 64
#define MBLK (TOKENS / BM)   // 32
#define NBLK (OUT_F / BN)    // 43
#define NWG  (MBLK * NBLK)   // 1376

static_assert(NWG % 8 == 0, "XCD swizzle requires nwg % 8 == 0");
static_assert(KT % 2 == 0, "double-buffer parity");

#define LDS_BUF   65536      // per buffer: A0|A1|B0|B1 regions of 16 KiB
#define LDS_TOTAL 131072

typedef __attribute__((ext_vector_type(4))) float f32x4;
typedef __attribute__((ext_vector_type(4))) int   i32x4;
typedef __attribute__((ext_vector_type(4))) unsigned short u16x4;

__device__ __forceinline__ unsigned short f2bf(float f) {
  unsigned int u = __builtin_bit_cast(unsigned int, f);
  u += 0x7FFFu + ((u >> 16) & 1u);
  return (unsigned short)(u >> 16);
}

__device__ __forceinline__ void gload_lds16(const void* g, void* l) {
  typedef const __attribute__((address_space(1))) unsigned int* gp_t;
  typedef __attribute__((address_space(3))) unsigned int* lp_t;
  __builtin_amdgcn_global_load_lds((gp_t)g, (lp_t)l, 16, 0, 0);
}

#define MFMA(d, a, b) \
  asm("v_mfma_f32_16x16x32_bf16 %0, %1, %2, %0" : "+v"(d) : "v"(a), "v"(b))

#define BARRIER __builtin_amdgcn_s_barrier()
#define LGKM0                                                  \
  do {                                                         \
    asm volatile("s_waitcnt lgkmcnt(0)" ::: "memory");         \
    __builtin_amdgcn_sched_barrier(0);                         \
  } while (0)
#define VMW(N) asm volatile("s_waitcnt vmcnt(" #N ")" ::: "memory")

// ---------------- convert pass: x fp32 -> bf16 ----------------
__global__ void cvt_x_kernel(const float* __restrict__ x,
                             unsigned short* __restrict__ xb, int n4) {
  int i = blockIdx.x * blockDim.x + threadIdx.x;
  int stride = gridDim.x * blockDim.x;
  for (int v = i; v < n4; v += stride) {
    f32x4 f = ((const f32x4*)x)[v];
    u16x4 r;
#pragma unroll
    for (int j = 0; j < 4; ++j) r[j] = f2bf(f[j]);
    ((u16x4*)xb)[v] = r;
  }
}

// ---------------- convert pass: w int32 in [-127,127] -> bf16 (exact) -------
__global__ void cvt_w_kernel(const int* __restrict__ w,
                             unsigned short* __restrict__ wb, int n4) {
  int i = blockIdx.x * blockDim.x + threadIdx.x;
  int stride = gridDim.x * blockDim.x;
  for (int c = i; c < n4; c += stride) {
    i32x4 v = ((const i32x4*)w)[c];
    u16x4 r;
#pragma unroll
    for (int j = 0; j < 4; ++j) r[j] = f2bf((float)v[j]);
    ((u16x4*)wb)[c] = r;
  }
}

// ---------------- bf16 MFMA GEMM, 256x256, 4-phase pipelined ----------------
// LDS region layout per buffer: A0 @0, A1 @16K, B0 @32K, B1 @48K.
// Region X_h holds operand X rows [0,256) x k-half h (32 cols, 64 B/row,
// 4 chunks of 16 B). Linear chunk c -> row r=c>>2, slot j=c&3; slot content
// pre-swizzled: holds global chunk j^(r&3) (both-sides involution).
__global__ __launch_bounds__(512) void gemm_bf16_kernel(
    const unsigned short* __restrict__ A,   // [TOKENS][IN_F] bf16
    const unsigned short* __restrict__ Bm,  // [OUT_F][IN_F] bf16
    const float* __restrict__ scale,        // [OUT_F]
    const float* __restrict__ bias,         // [OUT_F]
    float* __restrict__ C)                  // [TOKENS][OUT_F] fp32
{
  extern __shared__ char lds[];            // 128 KiB

  const int tid  = threadIdx.x;
  const int lane = tid & 63;
  const int wave = tid >> 6;   // 0..7
  const int wm   = wave >> 2;  // 0..1  (128-row half of M)
  const int wn   = wave & 3;   // 0..3  (64-col quarter of N)
  const int grp  = lane >> 4;  // 0..3
  const int rsel = lane & 15;  // 0..15

  // XCD-aware bijective swizzle
  int bid = blockIdx.x;
  int wg  = (bid & 7) * (NWG / 8) + (bid >> 3);
  const int m_idx = wg % MBLK;
  const int n_idx = wg / MBLK;
  const int row0 = m_idx * BM;
  const int col0 = n_idx * BN;

  // ---- staging addresses: thread covers region chunks c=tid and c=tid+512
  const int rA = tid >> 2;                       // rows 0..127 (chunk0)
  const int jg = (tid & 3) ^ (rA & 3);           // pre-swizzled slot (same for
                                                 // chunk1: rows +128 == 0 mod 4)
  const unsigned short* srcA0 = A  + (size_t)(row0 + rA) * IN_F + jg * 8;
  const unsigned short* srcA1 = srcA0 + (size_t)128 * IN_F;
  const unsigned short* srcB0 = Bm + (size_t)(col0 + rA) * IN_F + jg * 8;
  const unsigned short* srcB1 = srcB0 + (size_t)128 * IN_F;
  const int dBase = wave * 1024;                 // wave-uniform LDS chunk base

  auto stageA = [&](int bufoff, int half, int t) {
    char* base = lds + bufoff + half * 16384 + dBase;
    int koff = t * 64 + half * 32;
    gload_lds16(srcA0 + koff, base);
    gload_lds16(srcA1 + koff, base + 8192);
  };
  auto stageB = [&](int bufoff, int half, int t) {
    char* base = lds + bufoff + 32768 + half * 16384 + dBase;
    int koff = t * 64 + half * 32;
    gload_lds16(srcB0 + koff, base);
    gload_lds16(srcB1 + koff, base + 8192);
  };

  // ---- fragment ds_read offsets (swizzle slot is per-thread constant:
  // row = base + m*16 + rsel, (row&3) == (rsel&3) since bases are mult of 16)
  const int swz  = (grp ^ (rsel & 3)) << 4;
  const int aOff = (wm * 128 + rsel) * 64 + swz;
  const int bOff = 32768 + (wn * 64 + rsel) * 64 + swz;

#define DS_A(BO, H, M) \
  (*(const i32x4*)(lds + (BO) + (H) * 16384 + aOff + (M) * 1024))
#define DS_B(BO, H, N) \
  (*(const i32x4*)(lds + (BO) + (H) * 16384 + bOff + (N) * 1024))

  f32x4 zero = {0.f, 0.f, 0.f, 0.f};
  f32x4 acc[8][4];
#pragma unroll
  for (int m = 0; m < 8; ++m)
#pragma unroll
    for (int n = 0; n < 4; ++n) acc[m][n] = zero;

  // One K-tile = 4 phases. Stage plan (region-lifetime-proven):
  //   ph0: reads A_kk0(all m) + B_kk0(n0,1); stages B1(t+1) [other buf]
  //   ph1: reads B_kk0(n2,3);                stages A1(t+1) [other buf]
  //   ph2: reads A_kk1(all m) + B_kk1(n0,1); stages B0(t+2) [same buf]
  //   ph3: reads B_kk1(n2,3);                stages A0(t+2) [same buf]
  // vmcnt(8) before trailing barriers of ph1 (covers next ph2's A1,B1) and
  // ph3 (covers next tile ph0's A0,B0): exactly 4 stages newer may fly.
#define TILE(BO, T, DO_N1, DO_N2, VM1, VM3)                                    \
  {                                                                            \
    i32x4 ar[8], br0, br1;                                                     \
    /* ---- ph0 ---- */                                                        \
    _Pragma("unroll") for (int m = 0; m < 8; ++m) ar[m] = DS_A(BO, 0, m);      \
    br0 = DS_B(BO, 0, 0);                                                      \
    br1 = DS_B(BO, 0, 1);                                                      \
    if (DO_N1) stageB((BO) ^ LDS_BUF, 1, (T) + 1);                             \
    BARRIER;                                                                   \
    LGKM0;                                                                     \
    __builtin_amdgcn_s_setprio(1);                                             \
    _Pragma("unroll") for (int m = 0; m < 8; ++m) {                            \
      MFMA(acc[m][0], ar[m], br0);                                             \
      MFMA(acc[m][1], ar[m], br1);                                             \
    }                                                                          \
    __builtin_amdgcn_s_setprio(0);                                             \
    BARRIER;                                                                   \
    /* ---- ph1 ---- */                                                        \
    br0 = DS_B(BO, 0, 2);                                                      \
    br1 = DS_B(BO, 0, 3);                                                      \
    if (DO_N1) stageA((BO) ^ LDS_BUF, 1, (T) + 1);                             \
    BARRIER;                                                                   \
    LGKM0;                                                                     \
    __builtin_amdgcn_s_setprio(1);                                             \
    _Pragma("unroll") for (int m = 0; m < 8; ++m) {                            \
      MFMA(acc[m][2], ar[m], br0);                                             \
      MFMA(acc[m][3], ar[m], br1);                                             \
    }                                                                          \
    __builtin_amdgcn_s_setprio(0);                                             \
    VMW(VM1);                                                                  \
    BARRIER;                                                                   \
    /* ---- ph2 ---- */                                                        \
    _Pragma("unroll") for (int m = 0; m < 8; ++m) ar[m] = DS_A(BO, 1, m);      \
    br0 = DS_B(BO, 1, 0);                                                      \
    br1 = DS_B(BO, 1, 1);                                                      \
    if (DO_N2) stageB((BO), 0, (T) + 2);                                       \
    BARRIER;                                                                   \
    LGKM0;                                                                     \
    __builtin_amdgcn_s_setprio(1);                                             \
    _Pragma("unroll") for (int m = 0; m < 8; ++m) {                            \
      MFMA(acc[m][0], ar[m], br0);                                             \
      MFMA(acc[m][1], ar[m], br1);                                             \
    }                                                                          \
    __builtin_amdgcn_s_setprio(0);                                             \
    BARRIER;                                                                   \
    /* ---- ph3 ---- */                                                        \
    br0 = DS_B(BO, 1, 2);                                                      \
    br1 = DS_B(BO, 1, 3);                                                      \
    if (DO_N2) stageA((BO), 0, (T) + 2);                                       \
    BARRIER;                                                                   \
    LGKM0;                                                                     \
    __builtin_amdgcn_s_setprio(1);                                             \
    _Pragma("unroll") for (int m = 0; m < 8; ++m) {                            \
      MFMA(acc[m][2], ar[m], br0);                                             \
      MFMA(acc[m][3], ar[m], br1);                                             \
    }                                                                          \
    __builtin_amdgcn_s_setprio(0);                                             \
    VMW(VM3);                                                                  \
    BARRIER;                                                                   \
  }

  // Prologue: oldest->newest: A0(0),B0(0),B1(0),A1(0),B0(1),A0(1).
  stageA(0, 0, 0);
  stageB(0, 0, 0);
  stageB(0, 1, 0);
  stageA(0, 1, 0);
  stageB(LDS_BUF, 0, 1);
  stageA(LDS_BUF, 0, 1);
  VMW(8);     // oldest 2 stages (A0,B0 of tile 0) landed
  BARRIER;

  // Steady state: tiles 0..KT-3 fully staged-ahead.
  for (int t2 = 0; t2 < KT - 2; t2 += 2) {
    TILE(0,       t2,     true, true, 8, 8);
    TILE(LDS_BUF, t2 + 1, true, true, 8, 8);
  }
  // Tail: tile KT-2 (stages only B1/A1 of KT-1), tile KT-1 (drain).
  TILE(0,       KT - 2, true,  false, 8, 4);
  TILE(LDS_BUF, KT - 1, false, false, 0, 0);

#undef TILE
#undef DS_A
#undef DS_B

  // inline-asm MFMA bypasses hazard recognizer: pad before VALU reads acc
  asm volatile("s_nop 7\n\ts_nop 7" :::);

  // Epilogue: C/D layout col=lane&15, row=(lane>>4)*4+v
#pragma unroll
  for (int n = 0; n < 4; ++n) {
    int o = col0 + wn * 64 + n * 16 + rsel;
    float s  = scale[o];
    float bz = bias[o];
#pragma unroll
    for (int m = 0; m < 8; ++m) {
      int tr = row0 + wm * 128 + m * 16 + grp * 4;
      float* cp = C + (size_t)tr * OUT_F + o;
      f32x4 v = acc[m][n];
      cp[0 * (size_t)OUT_F] = v[0] * s + bz;
      cp[1 * (size_t)OUT_F] = v[1] * s + bz;
      cp[2 * (size_t)OUT_F] = v[2] * s + bz;
      cp[3 * (size_t)OUT_F] = v[3] * s + bz;
    }
  }
}

// ---------------- fallback (only if ws too small): naive fp32 ----------------
__global__ void gemm_naive_kernel(const float* __restrict__ x,
                                  const int* __restrict__ w,
                                  const float* __restrict__ sc,
                                  const float* __restrict__ bs,
                                  float* __restrict__ out) {
  long long idx = (long long)blockIdx.x * blockDim.x + threadIdx.x;
  long long total = (long long)TOKENS * OUT_F;
  if (idx >= total) return;
  int t = (int)(idx / OUT_F);
  int o = (int)(idx % OUT_F);
  const float* xp = x + (size_t)t * IN_F;
  const int* wp = w + (size_t)o * IN_F;
  float acc = 0.f;
  for (int k = 0; k < IN_F; k += 4) {
    i32x4 wv = *(const i32x4*)(wp + k);
    f32x4 xv = *(const f32x4*)(xp + k);
    acc += xv[0] * (float)wv[0] + xv[1] * (float)wv[1]
         + xv[2] * (float)wv[2] + xv[3] * (float)wv[3];
  }
  out[idx] = acc * sc[o] + bs[o];
}

extern "C" void kernel_launch(void* const* d_in, const int* in_sizes, int n_in,
                              void* d_out, int out_size, void* d_ws, size_t ws_size,
                              hipStream_t stream) {
  const float* x  = (const float*)d_in[0];
  const int*   qw = (const int*)d_in[1];     // int8 values materialized as int32
  const float* sc = (const float*)d_in[2];
  const float* bs = (const float*)d_in[3];
  float* out = (float*)d_out;

  const size_t xbBytes = (size_t)TOKENS * IN_F * sizeof(unsigned short); // 64 MiB
  const size_t wbBytes = (size_t)OUT_F * IN_F * sizeof(unsigned short);  // 86 MiB

  if (ws_size >= xbBytes + wbBytes) {
    unsigned short* xb = (unsigned short*)d_ws;
    unsigned short* wb = (unsigned short*)((char*)d_ws + xbBytes);
    cvt_x_kernel<<<2048, 256, 0, stream>>>(x, xb, TOKENS * IN_F / 4);
    cvt_w_kernel<<<2048, 256, 0, stream>>>(qw, wb, OUT_F * IN_F / 4);
    (void)hipFuncSetAttribute((const void*)gemm_bf16_kernel,
                              hipFuncAttributeMaxDynamicSharedMemorySize,
                              LDS_TOTAL);
    gemm_bf16_kernel<<<NWG, 512, LDS_TOTAL, stream>>>(xb, wb, sc, bs, out);
  } else {
    long long total = (long long)TOKENS * OUT_F;
    int blocks = (int)((total + 255) / 256);
    gemm_naive_kernel<<<blocks, 256, 0, stream>>>(x, qw, sc, bs, out);
  }
}

// Round 5
// 807.314 us; speedup vs baseline: 1.1994x; 1.1994x over previous
//
#include <hip/hip_runtime.h>
#include <stdint.h>

// WeightOnlyInt8Linear: out[t,o] = sum_k x[t,k] * (int8 w[o,k] * scale[o]) + bias[o]
// M=8192, K=4096, N=11008. x fp32, w int8-as-int32 (harness), out fp32.
// Round 4: 4-phase fine schedule with 128B-row LDS regions (conflict-free
// 8-slot XOR swizzle, proven 0-conflict in r1/r2) + counted-vmcnt deep
// prefetch (depth 5-7 phases). Regions per buffer: AL/AH/BL/BH, 16 KiB each,
// split by OUTPUT-fragment rows (not k), so rows stay 64 cols = 128 B.
//   AL: A rows {0-63, 128-191}   (fragment m0-3 of both wm halves)
//   AH: A rows {64-127, 192-255} (fragment m4-7)
//   BL: B rows {wn*64+0..31}     (fragment n0-1)
//   BH: B rows {wn*64+32..63}    (fragment n2-3)
// Phases: ph0 reads AL+BL, ph1 reads BH + stages AL/BL(t+2),
//         ph2 reads AH + stages BH(t+2), ph3 stages AH(t+2) (regs reused).

#define TOKENS 8192
#define IN_F   4096
#define OUT_F  11008

#define BM 256
#define BN 256
#define BK 64
#define KT   (IN_F / BK)     // 64
#define MBLK (TOKENS / BM)   // 32
#define NBLK (OUT_F / BN)    // 43
#define NWG  (MBLK * NBLK)   // 1376

static_assert(NWG % 8 == 0, "XCD swizzle requires nwg % 8 == 0");
static_assert(KT % 2 == 0, "double-buffer parity");

#define LDS_BUF   65536      // per buffer: AL|AH|BL|BH regions of 16 KiB
#define LDS_TOTAL 131072

typedef __attribute__((ext_vector_type(4))) float f32x4;
typedef __attribute__((ext_vector_type(4))) int   i32x4;
typedef __attribute__((ext_vector_type(4))) unsigned short u16x4;

__device__ __forceinline__ unsigned short f2bf(float f) {
  unsigned int u = __builtin_bit_cast(unsigned int, f);
  u += 0x7FFFu + ((u >> 16) & 1u);
  return (unsigned short)(u >> 16);
}

__device__ __forceinline__ void gload_lds16(const void* g, void* l) {
  typedef const __attribute__((address_space(1))) unsigned int* gp_t;
  typedef __attribute__((address_space(3))) unsigned int* lp_t;
  __builtin_amdgcn_global_load_lds((gp_t)g, (lp_t)l, 16, 0, 0);
}

#define MFMA(d, a, b) \
  asm("v_mfma_f32_16x16x32_bf16 %0, %1, %2, %0" : "+v"(d) : "v"(a), "v"(b))

#define BARRIER __builtin_amdgcn_s_barrier()
#define LGKM0                                                  \
  do {                                                         \
    asm volatile("s_waitcnt lgkmcnt(0)" ::: "memory");         \
    __builtin_amdgcn_sched_barrier(0);                         \
  } while (0)
#define VMW_(N) asm volatile("s_waitcnt vmcnt(" #N ")" ::: "memory")
#define VMW(N) VMW_(N)

// ---------------- convert pass: x fp32 -> bf16 ----------------
__global__ void cvt_x_kernel(const float* __restrict__ x,
                             unsigned short* __restrict__ xb, int n4) {
  int i = blockIdx.x * blockDim.x + threadIdx.x;
  int stride = gridDim.x * blockDim.x;
  for (int v = i; v < n4; v += stride) {
    f32x4 f = ((const f32x4*)x)[v];
    u16x4 r;
#pragma unroll
    for (int j = 0; j < 4; ++j) r[j] = f2bf(f[j]);
    ((u16x4*)xb)[v] = r;
  }
}

// ---------------- convert pass: w int32 in [-127,127] -> bf16 (exact) -------
__global__ void cvt_w_kernel(const int* __restrict__ w,
                             unsigned short* __restrict__ wb, int n4) {
  int i = blockIdx.x * blockDim.x + threadIdx.x;
  int stride = gridDim.x * blockDim.x;
  for (int c = i; c < n4; c += stride) {
    i32x4 v = ((const i32x4*)w)[c];
    u16x4 r;
#pragma unroll
    for (int j = 0; j < 4; ++j) r[j] = f2bf((float)v[j]);
    ((u16x4*)wb)[c] = r;
  }
}

// ---------------- bf16 MFMA GEMM, 256x256, 4-phase pipelined ----------------
// Region internal layout: 128 rows x 128 B; row r, slot j (16 B) holds global
// chunk j ^ (r&7) (both-sides involution). ds_read slot for fragment chunk
// jw = kk*4+grp at region row rr: jw ^ (rr&7); rr&7 == rsel&7 always.
__global__ __launch_bounds__(512) void gemm_bf16_kernel(
    const unsigned short* __restrict__ A,   // [TOKENS][IN_F] bf16
    const unsigned short* __restrict__ Bm,  // [OUT_F][IN_F] bf16
    const float* __restrict__ scale,        // [OUT_F]
    const float* __restrict__ bias,         // [OUT_F]
    float* __restrict__ C)                  // [TOKENS][OUT_F] fp32
{
  extern __shared__ char lds[];            // 128 KiB

  const int tid  = threadIdx.x;
  const int lane = tid & 63;
  const int wave = tid >> 6;   // 0..7
  const int wm   = wave >> 2;  // 0..1  (128-row half of M)
  const int wn   = wave & 3;   // 0..3  (64-col quarter of N)
  const int grp  = lane >> 4;  // 0..3
  const int rsel = lane & 15;  // 0..15

  // XCD-aware bijective swizzle
  int bid = blockIdx.x;
  int wg  = (bid & 7) * (NWG / 8) + (bid >> 3);
  const int m_idx = wg % MBLK;
  const int n_idx = wg / MBLK;
  const int row0 = m_idx * BM;
  const int col0 = n_idx * BN;

  // ---- staging: per region 1024 chunks of 16B; thread covers chunks
  // c = p*512 + tid (p=0,1). r = c>>3 (region row), j = c&7, src slot j^(r&7).
  const int r0  = tid >> 3;                      // 0..63 (p=0); p=1 adds 64
  const int jg  = (tid & 7) ^ (r0 & 7);          // same for p=1 (64 = 0 mod 8)
  // global row mapping per region (see header comment):
  const int gAL0 = r0;                           // p0: region rows 0..63
  const int gAL1 = 128 + r0;                     // p1: region rows 64..127
  const int gBL0 = r0 + (r0 & 32);
  const int gBL1 = 128 + r0 + (r0 & 32);
  const unsigned short* pAL0 = A  + (size_t)(row0 + gAL0) * IN_F + jg * 8;
  const unsigned short* pAL1 = A  + (size_t)(row0 + gAL1) * IN_F + jg * 8;
  const unsigned short* pAH0 = pAL0 + (size_t)64 * IN_F;
  const unsigned short* pAH1 = pAL1 + (size_t)64 * IN_F;
  const unsigned short* pBL0 = Bm + (size_t)(col0 + gBL0) * IN_F + jg * 8;
  const unsigned short* pBL1 = Bm + (size_t)(col0 + gBL1) * IN_F + jg * 8;
  const unsigned short* pBH0 = pBL0 + (size_t)32 * IN_F;
  const unsigned short* pBH1 = pBL1 + (size_t)32 * IN_F;
  const int stBase = wave * 1024;                // wave-uniform LDS offset

  auto stALBL = [&](int bo, int t2) {            // 4 gloads
    const int ko = t2 * 64;
    gload_lds16(pAL0 + ko, lds + bo + 0     + stBase);
    gload_lds16(pAL1 + ko, lds + bo + 8192  + stBase);
    gload_lds16(pBL0 + ko, lds + bo + 32768 + stBase);
    gload_lds16(pBL1 + ko, lds + bo + 40960 + stBase);
  };
  auto stBH = [&](int bo, int t2) {              // 2 gloads
    const int ko = t2 * 64;
    gload_lds16(pBH0 + ko, lds + bo + 49152 + stBase);
    gload_lds16(pBH1 + ko, lds + bo + 57344 + stBase);
  };
  auto stAH = [&](int bo, int t2) {              // 2 gloads
    const int ko = t2 * 64;
    gload_lds16(pAH0 + ko, lds + bo + 16384 + stBase);
    gload_lds16(pAH1 + ko, lds + bo + 24576 + stBase);
  };

  // ---- fragment ds_read constants
  const int swz0  = ((grp) ^ (rsel & 7)) << 4;   // kk=0 slot byte offset
  const int swz1  = swz0 ^ 64;                   // kk=1: jw+4 -> XOR bit2
  const int aBase = wm * 8192 + rsel * 128;      // within AL/AH region
  const int bBase = wn * 4096 + rsel * 128;      // within BL/BH region

  f32x4 zero = {0.f, 0.f, 0.f, 0.f};
  f32x4 acc[8][4];
#pragma unroll
  for (int m = 0; m < 8; ++m)
#pragma unroll
    for (int n = 0; n < 4; ++n) acc[m][n] = zero;

#define DS_AL(BO, MI, SW) (*(const i32x4*)(lds + (BO) + 0     + aBase + (MI)*2048 + (SW)))
#define DS_AH(BO, MI, SW) (*(const i32x4*)(lds + (BO) + 16384 + aBase + (MI)*2048 + (SW)))
#define DS_BL(BO, NI, SW) (*(const i32x4*)(lds + (BO) + 32768 + bBase + (NI)*2048 + (SW)))
#define DS_BH(BO, NI, SW) (*(const i32x4*)(lds + (BO) + 49152 + bBase + (NI)*2048 + (SW)))

  // Counted-vmcnt plan (per-thread gload batches, oldest->newest):
  //   tile t issues: ph1: AL,BL(t+2) [4]; ph2: BH(t+2) [2]; ph3: AH(t+2) [2]
  //   consumers: ph0 reads AL/BL(t); ph1 reads BH(t); ph2 reads AH(t)
  //   waits (end of phase, before trailing barrier):
  //     ph0: VMW(10)  -> BH(t) landed    ph1: VMW(12) -> AH(t) landed
  //     ph3: VMW(12)  -> AL/BL(t+1) landed
#define TILE(BO, T, DO_STAGE, W0, W1, W3)                                      \
  {                                                                            \
    i32x4 arLo[8], arHi[8], brLo[4], brHi[4];                                  \
    /* ---- ph0: read A-lo + B-lo ---- */                                      \
    _Pragma("unroll") for (int m = 0; m < 4; ++m) {                            \
      arLo[m * 2]     = DS_AL(BO, m, swz0);                                    \
      arLo[m * 2 + 1] = DS_AL(BO, m, swz1);                                    \
    }                                                                          \
    _Pragma("unroll") for (int n = 0; n < 2; ++n) {                            \
      brLo[n * 2]     = DS_BL(BO, n, swz0);                                    \
      brLo[n * 2 + 1] = DS_BL(BO, n, swz1);                                    \
    }                                                                          \
    BARRIER;                                                                   \
    LGKM0;                                                                     \
    __builtin_amdgcn_s_setprio(1);                                             \
    _Pragma("unroll") for (int m = 0; m < 4; ++m)                              \
      _Pragma("unroll") for (int n = 0; n < 2; ++n)                            \
        _Pragma("unroll") for (int kk = 0; kk < 2; ++kk)                       \
          MFMA(acc[m][n], arLo[m * 2 + kk], brLo[n * 2 + kk]);                 \
    __builtin_amdgcn_s_setprio(0);                                             \
    VMW(W0);                                                                   \
    BARRIER;                                                                   \
    /* ---- ph1: read B-hi; stage AL,BL(T+2) ---- */                           \
    _Pragma("unroll") for (int n = 0; n < 2; ++n) {                            \
      brHi[n * 2]     = DS_BH(BO, n, swz0);                                    \
      brHi[n * 2 + 1] = DS_BH(BO, n, swz1);                                    \
    }                                                                          \
    if (DO_STAGE) stALBL((BO), (T) + 2);                                       \
    BARRIER;                                                                   \
    LGKM0;                                                                     \
    __builtin_amdgcn_s_setprio(1);                                             \
    _Pragma("unroll") for (int m = 0; m < 4; ++m)                              \
      _Pragma("unroll") for (int n = 0; n < 2; ++n)                            \
        _Pragma("unroll") for (int kk = 0; kk < 2; ++kk)                       \
          MFMA(acc[m][n + 2], arLo[m * 2 + kk], brHi[n * 2 + kk]);             \
    __builtin_amdgcn_s_setprio(0);                                             \
    VMW(W1);                                                                   \
    BARRIER;                                                                   \
    /* ---- ph2: read A-hi; stage BH(T+2) ---- */                              \
    _Pragma("unroll") for (int m = 0; m < 4; ++m) {                            \
      arHi[m * 2]     = DS_AH(BO, m, swz0);                                    \
      arHi[m * 2 + 1] = DS_AH(BO, m, swz1);                                    \
    }                                                                          \
    if (DO_STAGE) stBH((BO), (T) + 2);                                         \
    BARRIER;                                                                   \
    LGKM0;                                                                     \
    __builtin_amdgcn_s_setprio(1);                                             \
    _Pragma("unroll") for (int m = 0; m < 4; ++m)                              \
      _Pragma("unroll") for (int n = 0; n < 2; ++n)                            \
        _Pragma("unroll") for (int kk = 0; kk < 2; ++kk)                       \
          MFMA(acc[m + 4][n + 2], arHi[m * 2 + kk], brHi[n * 2 + kk]);         \
    __builtin_amdgcn_s_setprio(0);                                             \
    BARRIER;                                                                   \
    /* ---- ph3: stage AH(T+2); MFMA from held regs ---- */                    \
    if (DO_STAGE) stAH((BO), (T) + 2);                                         \
    __builtin_amdgcn_s_setprio(1);                                             \
    _Pragma("unroll") for (int m = 0; m < 4; ++m)                              \
      _Pragma("unroll") for (int n = 0; n < 2; ++n)                            \
        _Pragma("unroll") for (int kk = 0; kk < 2; ++kk)                       \
          MFMA(acc[m + 4][n], arHi[m * 2 + kk], brLo[n * 2 + kk]);             \
    __builtin_amdgcn_s_setprio(0);                                             \
    VMW(W3);                                                                   \
    BARRIER;                                                                   \
  }

  // Prologue: stage tiles 0 and 1 in steady-state issue order.
  stALBL(0, 0);        stBH(0, 0);        stAH(0, 0);
  stALBL(LDS_BUF, 1);  stBH(LDS_BUF, 1);  stAH(LDS_BUF, 1);
  VMW(12);   // oldest 4 (AL,BL of tile 0) landed; 12 newer stay in flight
  BARRIER;

  for (int t2 = 0; t2 < KT - 2; t2 += 2) {
    TILE(0,       t2,     true, 10, 12, 12);
    TILE(LDS_BUF, t2 + 1, true, 10, 12, 12);
  }
  TILE(0,       KT - 2, false, 10, 8, 4);
  TILE(LDS_BUF, KT - 1, false, 2, 0, 0);

#undef TILE
#undef DS_AL
#undef DS_AH
#undef DS_BL
#undef DS_BH

  // inline-asm MFMA bypasses hazard recognizer: pad before VALU reads acc
  asm volatile("s_nop 7\n\ts_nop 7" :::);

  // Epilogue: C/D layout col=lane&15, row=(lane>>4)*4+v (verified r1-r3)
#pragma unroll
  for (int n = 0; n < 4; ++n) {
    int o = col0 + wn * 64 + n * 16 + rsel;
    float s  = scale[o];
    float bz = bias[o];
#pragma unroll
    for (int m = 0; m < 8; ++m) {
      int tr = row0 + wm * 128 + m * 16 + grp * 4;
      float* cp = C + (size_t)tr * OUT_F + o;
      f32x4 v = acc[m][n];
      cp[0 * (size_t)OUT_F] = v[0] * s + bz;
      cp[1 * (size_t)OUT_F] = v[1] * s + bz;
      cp[2 * (size_t)OUT_F] = v[2] * s + bz;
      cp[3 * (size_t)OUT_F] = v[3] * s + bz;
    }
  }
}

// ---------------- fallback (only if ws too small): naive fp32 ----------------
__global__ void gemm_naive_kernel(const float* __restrict__ x,
                                  const int* __restrict__ w,
                                  const float* __restrict__ sc,
                                  const float* __restrict__ bs,
                                  float* __restrict__ out) {
  long long idx = (long long)blockIdx.x * blockDim.x + threadIdx.x;
  long long total = (long long)TOKENS * OUT_F;
  if (idx >= total) return;
  int t = (int)(idx / OUT_F);
  int o = (int)(idx % OUT_F);
  const float* xp = x + (size_t)t * IN_F;
  const int* wp = w + (size_t)o * IN_F;
  float acc = 0.f;
  for (int k = 0; k < IN_F; k += 4) {
    i32x4 wv = *(const i32x4*)(wp + k);
    f32x4 xv = *(const f32x4*)(xp + k);
    acc += xv[0] * (float)wv[0] + xv[1] * (float)wv[1]
         + xv[2] * (float)wv[2] + xv[3] * (float)wv[3];
  }
  out[idx] = acc * sc[o] + bs[o];
}

extern "C" void kernel_launch(void* const* d_in, const int* in_sizes, int n_in,
                              void* d_out, int out_size, void* d_ws, size_t ws_size,
                              hipStream_t stream) {
  const float* x  = (const float*)d_in[0];
  const int*   qw = (const int*)d_in[1];     // int8 values materialized as int32
  const float* sc = (const float*)d_in[2];
  const float* bs = (const float*)d_in[3];
  float* out = (float*)d_out;

  const size_t xbBytes = (size_t)TOKENS * IN_F * sizeof(unsigned short); // 64 MiB
  const size_t wbBytes = (size_t)OUT_F * IN_F * sizeof(unsigned short);  // 86 MiB

  if (ws_size >= xbBytes + wbBytes) {
    unsigned short* xb = (unsigned short*)d_ws;
    unsigned short* wb = (unsigned short*)((char*)d_ws + xbBytes);
    cvt_x_kernel<<<2048, 256, 0, stream>>>(x, xb, TOKENS * IN_F / 4);
    cvt_w_kernel<<<2048, 256, 0, stream>>>(qw, wb, OUT_F * IN_F / 4);
    (void)hipFuncSetAttribute((const void*)gemm_bf16_kernel,
                              hipFuncAttributeMaxDynamicSharedMemorySize,
                              LDS_TOTAL);
    gemm_bf16_kernel<<<NWG, 512, LDS_TOTAL, stream>>>(xb, wb, sc, bs, out);
  } else {
    long long total = (long long)TOKENS * OUT_F;
    int blocks = (int)((total + 255) / 256);
    gemm_naive_kernel<<<blocks, 256, 0, stream>>>(x, qw, sc, bs, out);
  }
}

// Round 6
// 519.998 us; speedup vs baseline: 1.8621x; 1.5525x over previous
//
#include <hip/hip_runtime.h>
#include <stdint.h>

// WeightOnlyInt8Linear: out[t,o] = sum_k x[t,k] * (int8 w[o,k] * scale[o]) + bias[o]
// M=8192, K=4096, N=11008. x fp32, w int8-as-int32 (harness), out fp32.
// Round 5: int8 MFMA (v_mfma_i32_16x16x64_i8, 2x bf16 OP rate, exact int32
// accumulation). x quantized per-token (absmax/127, RTN) -> int8; w cast to
// int8 (exact). Same proven 4-phase schedule as round 4 (0 bank conflicts):
// 256x256 tile, BK=128 int8 (128 B rows, 8-slot XOR swizzle), 8 waves,
// double-buffered 128 KiB LDS, counted-vmcnt deep prefetch.
// Epilogue: out = acc_i32 * sx[token] * scale[o] + bias[o].

#define TOKENS 8192
#define IN_F   4096
#define OUT_F  11008

#define BM 256
#define BN 256
#define BK 128               // int8 k-slab per LDS tile
#define KT   (IN_F / BK)     // 32
#define MBLK (TOKENS / BM)   // 32
#define NBLK (OUT_F / BN)    // 43
#define NWG  (MBLK * NBLK)   // 1376

static_assert(NWG % 8 == 0, "XCD swizzle requires nwg % 8 == 0");
static_assert(KT % 2 == 0, "double-buffer parity");

#define LDS_BUF   65536      // per buffer: AL|AH|BL|BH regions of 16 KiB
#define LDS_TOTAL 131072

typedef __attribute__((ext_vector_type(4))) float f32x4;
typedef __attribute__((ext_vector_type(4))) int   i32x4;

__device__ __forceinline__ void gload_lds16(const void* g, void* l) {
  typedef const __attribute__((address_space(1))) unsigned int* gp_t;
  typedef __attribute__((address_space(3))) unsigned int* lp_t;
  __builtin_amdgcn_global_load_lds((gp_t)g, (lp_t)l, 16, 0, 0);
}

#define MFMA(d, a, b) \
  asm("v_mfma_i32_16x16x64_i8 %0, %1, %2, %0" : "+v"(d) : "v"(a), "v"(b))

#define BARRIER __builtin_amdgcn_s_barrier()
#define LGKM0                                                  \
  do {                                                         \
    asm volatile("s_waitcnt lgkmcnt(0)" ::: "memory");         \
    __builtin_amdgcn_sched_barrier(0);                         \
  } while (0)
#define VMW_(N) asm volatile("s_waitcnt vmcnt(" #N ")" ::: "memory")
#define VMW(N) VMW_(N)

// ---------------- quantize x: per-token absmax -> int8 + sx ----------------
__global__ __launch_bounds__(256) void quant_x_kernel(
    const float* __restrict__ x, signed char* __restrict__ xq,
    float* __restrict__ sx) {
  const int row = blockIdx.x;
  const int tid = threadIdx.x;
  const float* xr = x + (size_t)row * IN_F;
  f32x4 v[4];
#pragma unroll
  for (int p = 0; p < 4; ++p) v[p] = ((const f32x4*)xr)[tid + 256 * p];
  float am = 0.f;
#pragma unroll
  for (int p = 0; p < 4; ++p)
#pragma unroll
    for (int j = 0; j < 4; ++j) am = fmaxf(am, fabsf(v[p][j]));
#pragma unroll
  for (int off = 32; off; off >>= 1) am = fmaxf(am, __shfl_xor(am, off, 64));
  __shared__ float wmax[4];
  if ((tid & 63) == 0) wmax[tid >> 6] = am;
  __syncthreads();
  am = fmaxf(fmaxf(wmax[0], wmax[1]), fmaxf(wmax[2], wmax[3]));
  const float inv = (am > 0.f) ? 127.0f / am : 0.f;
  if (tid == 0) sx[row] = (am > 0.f) ? am / 127.0f : 1.0f;
  int* xqi = (int*)(xq + (size_t)row * IN_F);
#pragma unroll
  for (int p = 0; p < 4; ++p) {
    int pk = 0;
#pragma unroll
    for (int j = 0; j < 4; ++j) {
      int q = (int)rintf(v[p][j] * inv);   // |x|<=am -> q in [-127,127]
      pk |= (q & 0xff) << (8 * j);
    }
    xqi[tid + 256 * p] = pk;
  }
}

// ---------------- convert w: int32 (values in [-127,127]) -> int8 ----------
__global__ void cvt_w_kernel(const int* __restrict__ w,
                             signed char* __restrict__ wq, int n16) {
  int i = blockIdx.x * blockDim.x + threadIdx.x;
  int stride = gridDim.x * blockDim.x;
  for (int c = i; c < n16; c += stride) {
    const i32x4* src = (const i32x4*)w + (size_t)c * 4;
    i32x4 outv;
#pragma unroll
    for (int q = 0; q < 4; ++q) {
      i32x4 v = src[q];
      outv[q] = (v[0] & 0xff) | ((v[1] & 0xff) << 8) |
                ((v[2] & 0xff) << 16) | (v[3] << 24);
    }
    ((i32x4*)wq)[c] = outv;
  }
}

// ---------------- int8 MFMA GEMM, 256x256, 4-phase pipelined ----------------
// Regions per buffer (16 KiB = 128 rows x 128 B, row = one K-slab of 128 i8):
//   AL: A rows {0-63,128-191}; AH: {64-127,192-255};
//   BL: B rows {wn*64+0..31};  BH: {wn*64+32..63}.
// Row r slot j (16 B) holds global chunk j^(r&7) (both-sides involution;
// 0 conflicts measured r4). Fragment chunk for MFMA kk (k=kk*64+grp*16+b):
// slot jw = kk*4+grp -> byte ((kk*4+grp)^(rsel&7))<<4 = swz0 ^ kk*64.
__global__ __launch_bounds__(512) void gemm_i8_kernel(
    const signed char* __restrict__ A,   // [TOKENS][IN_F] int8
    const signed char* __restrict__ Bm,  // [OUT_F][IN_F] int8
    const float* __restrict__ sx,        // [TOKENS] per-token x scale
    const float* __restrict__ scale,     // [OUT_F]
    const float* __restrict__ bias,      // [OUT_F]
    float* __restrict__ C)               // [TOKENS][OUT_F] fp32
{
  extern __shared__ char lds[];          // 128 KiB

  const int tid  = threadIdx.x;
  const int lane = tid & 63;
  const int wave = tid >> 6;   // 0..7
  const int wm   = wave >> 2;  // 0..1
  const int wn   = wave & 3;   // 0..3
  const int grp  = lane >> 4;  // 0..3
  const int rsel = lane & 15;  // 0..15

  int bid = blockIdx.x;
  int wg  = (bid & 7) * (NWG / 8) + (bid >> 3);
  const int m_idx = wg % MBLK;
  const int n_idx = wg / MBLK;
  const int row0 = m_idx * BM;
  const int col0 = n_idx * BN;

  // staging: per region 1024 chunks of 16 B; thread covers c = p*512+tid.
  const int r0  = tid >> 3;                      // region row (p=0); p=1: +64
  const int jg  = (tid & 7) ^ (r0 & 7);          // pre-swizzled slot
  const int gAL0 = r0;
  const int gAL1 = 128 + r0;
  const int gBL0 = r0 + (r0 & 32);
  const int gBL1 = 128 + r0 + (r0 & 32);
  const signed char* pAL0 = A  + (size_t)(row0 + gAL0) * IN_F + jg * 16;
  const signed char* pAL1 = A  + (size_t)(row0 + gAL1) * IN_F + jg * 16;
  const signed char* pAH0 = pAL0 + (size_t)64 * IN_F;
  const signed char* pAH1 = pAL1 + (size_t)64 * IN_F;
  const signed char* pBL0 = Bm + (size_t)(col0 + gBL0) * IN_F + jg * 16;
  const signed char* pBL1 = Bm + (size_t)(col0 + gBL1) * IN_F + jg * 16;
  const signed char* pBH0 = pBL0 + (size_t)32 * IN_F;
  const signed char* pBH1 = pBL1 + (size_t)32 * IN_F;
  const int stBase = wave * 1024;

  auto stALBL = [&](int bo, int t2) {            // 4 gloads
    const int ko = t2 * BK;
    gload_lds16(pAL0 + ko, lds + bo + 0     + stBase);
    gload_lds16(pAL1 + ko, lds + bo + 8192  + stBase);
    gload_lds16(pBL0 + ko, lds + bo + 32768 + stBase);
    gload_lds16(pBL1 + ko, lds + bo + 40960 + stBase);
  };
  auto stBH = [&](int bo, int t2) {              // 2 gloads
    const int ko = t2 * BK;
    gload_lds16(pBH0 + ko, lds + bo + 49152 + stBase);
    gload_lds16(pBH1 + ko, lds + bo + 57344 + stBase);
  };
  auto stAH = [&](int bo, int t2) {              // 2 gloads
    const int ko = t2 * BK;
    gload_lds16(pAH0 + ko, lds + bo + 16384 + stBase);
    gload_lds16(pAH1 + ko, lds + bo + 24576 + stBase);
  };

  const int swz0  = (grp ^ (rsel & 7)) << 4;
  const int swz1  = swz0 ^ 64;
  const int aBase = wm * 8192 + rsel * 128;
  const int bBase = wn * 4096 + rsel * 128;

  i32x4 zero = {0, 0, 0, 0};
  i32x4 acc[8][4];
#pragma unroll
  for (int m = 0; m < 8; ++m)
#pragma unroll
    for (int n = 0; n < 4; ++n) acc[m][n] = zero;

#define DS_AL(BO, MI, SW) (*(const i32x4*)(lds + (BO) + 0     + aBase + (MI)*2048 + (SW)))
#define DS_AH(BO, MI, SW) (*(const i32x4*)(lds + (BO) + 16384 + aBase + (MI)*2048 + (SW)))
#define DS_BL(BO, NI, SW) (*(const i32x4*)(lds + (BO) + 32768 + bBase + (NI)*2048 + (SW)))
#define DS_BH(BO, NI, SW) (*(const i32x4*)(lds + (BO) + 49152 + bBase + (NI)*2048 + (SW)))

  // Schedule + counted-vmcnt plan identical to round 4 (verified):
  //   ph1 stages ALBL(t+2)[4], ph2 stages BH(t+2)[2], ph3 stages AH(t+2)[2]
  //   waits: ph0 end VMW(10) -> BH(t) landed; ph1 end VMW(12) -> AH(t);
  //          ph3 end VMW(12) -> ALBL(t+1).
#define TILE(BO, T, DO_STAGE, W0, W1, W3)                                      \
  {                                                                            \
    i32x4 arLo[8], arHi[8], brLo[4], brHi[4];                                  \
    /* ---- ph0: read A-lo + B-lo ---- */                                      \
    _Pragma("unroll") for (int m = 0; m < 4; ++m) {                            \
      arLo[m * 2]     = DS_AL(BO, m, swz0);                                    \
      arLo[m * 2 + 1] = DS_AL(BO, m, swz1);                                    \
    }                                                                          \
    _Pragma("unroll") for (int n = 0; n < 2; ++n) {                            \
      brLo[n * 2]     = DS_BL(BO, n, swz0);                                    \
      brLo[n * 2 + 1] = DS_BL(BO, n, swz1);                                    \
    }                                                                          \
    BARRIER;                                                                   \
    LGKM0;                                                                     \
    __builtin_amdgcn_s_setprio(1);                                             \
    _Pragma("unroll") for (int m = 0; m < 4; ++m)                              \
      _Pragma("unroll") for (int n = 0; n < 2; ++n)                            \
        _Pragma("unroll") for (int kk = 0; kk < 2; ++kk)                       \
          MFMA(acc[m][n], arLo[m * 2 + kk], brLo[n * 2 + kk]);                 \
    __builtin_amdgcn_s_setprio(0);                                             \
    VMW(W0);                                                                   \
    BARRIER;                                                                   \
    /* ---- ph1: read B-hi; stage AL,BL(T+2) ---- */                           \
    _Pragma("unroll") for (int n = 0; n < 2; ++n) {                            \
      brHi[n * 2]     = DS_BH(BO, n, swz0);                                    \
      brHi[n * 2 + 1] = DS_BH(BO, n, swz1);                                    \
    }                                                                          \
    if (DO_STAGE) stALBL((BO), (T) + 2);                                       \
    BARRIER;                                                                   \
    LGKM0;                                                                     \
    __builtin_amdgcn_s_setprio(1);                                             \
    _Pragma("unroll") for (int m = 0; m < 4; ++m)                              \
      _Pragma("unroll") for (int n = 0; n < 2; ++n)                            \
        _Pragma("unroll") for (int kk = 0; kk < 2; ++kk)                       \
          MFMA(acc[m][n + 2], arLo[m * 2 + kk], brHi[n * 2 + kk]);             \
    __builtin_amdgcn_s_setprio(0);                                             \
    VMW(W1);                                                                   \
    BARRIER;                                                                   \
    /* ---- ph2: read A-hi; stage BH(T+2) ---- */                              \
    _Pragma("unroll") for (int m = 0; m < 4; ++m) {                            \
      arHi[m * 2]     = DS_AH(BO, m, swz0);                                    \
      arHi[m * 2 + 1] = DS_AH(BO, m, swz1);                                    \
    }                                                                          \
    if (DO_STAGE) stBH((BO), (T) + 2);                                         \
    BARRIER;                                                                   \
    LGKM0;                                                                     \
    __builtin_amdgcn_s_setprio(1);                                             \
    _Pragma("unroll") for (int m = 0; m < 4; ++m)                              \
      _Pragma("unroll") for (int n = 0; n < 2; ++n)                            \
        _Pragma("unroll") for (int kk = 0; kk < 2; ++kk)                       \
          MFMA(acc[m + 4][n + 2], arHi[m * 2 + kk], brHi[n * 2 + kk]);         \
    __builtin_amdgcn_s_setprio(0);                                             \
    BARRIER;                                                                   \
    /* ---- ph3: stage AH(T+2); MFMA from held regs ---- */                    \
    if (DO_STAGE) stAH((BO), (T) + 2);                                         \
    __builtin_amdgcn_s_setprio(1);                                             \
    _Pragma("unroll") for (int m = 0; m < 4; ++m)                              \
      _Pragma("unroll") for (int n = 0; n < 2; ++n)                            \
        _Pragma("unroll") for (int kk = 0; kk < 2; ++kk)                       \
          MFMA(acc[m + 4][n], arHi[m * 2 + kk], brLo[n * 2 + kk]);             \
    __builtin_amdgcn_s_setprio(0);                                             \
    VMW(W3);                                                                   \
    BARRIER;                                                                   \
  }

  // Prologue: stage slabs 0 and 1 in steady-state issue order.
  stALBL(0, 0);        stBH(0, 0);        stAH(0, 0);
  stALBL(LDS_BUF, 1);  stBH(LDS_BUF, 1);  stAH(LDS_BUF, 1);
  VMW(12);
  BARRIER;

  for (int t2 = 0; t2 < KT - 2; t2 += 2) {
    TILE(0,       t2,     true, 10, 12, 12);
    TILE(LDS_BUF, t2 + 1, true, 10, 12, 12);
  }
  TILE(0,       KT - 2, false, 10, 8, 4);
  TILE(LDS_BUF, KT - 1, false, 2, 0, 0);

#undef TILE
#undef DS_AL
#undef DS_AH
#undef DS_BL
#undef DS_BH

  asm volatile("s_nop 7\n\ts_nop 7" :::);

  // Epilogue: C/D layout col=lane&15, row=(lane>>4)*4+v (dtype-independent).
  // out = acc * sx[token] * scale[o] + bias[o]; rows tr..tr+3 contiguous.
#pragma unroll
  for (int n = 0; n < 4; ++n) {
    int o = col0 + wn * 64 + n * 16 + rsel;
    float s  = scale[o];
    float bz = bias[o];
#pragma unroll
    for (int m = 0; m < 8; ++m) {
      int tr = row0 + wm * 128 + m * 16 + grp * 4;
      const f32x4 sxv = *(const f32x4*)(sx + tr);
      float* cp = C + (size_t)tr * OUT_F + o;
      i32x4 v = acc[m][n];
      cp[0 * (size_t)OUT_F] = (float)v[0] * (sxv[0] * s) + bz;
      cp[1 * (size_t)OUT_F] = (float)v[1] * (sxv[1] * s) + bz;
      cp[2 * (size_t)OUT_F] = (float)v[2] * (sxv[2] * s) + bz;
      cp[3 * (size_t)OUT_F] = (float)v[3] * (sxv[3] * s) + bz;
    }
  }
}

// ---------------- fallback (only if ws too small): naive fp32 ----------------
__global__ void gemm_naive_kernel(const float* __restrict__ x,
                                  const int* __restrict__ w,
                                  const float* __restrict__ sc,
                                  const float* __restrict__ bs,
                                  float* __restrict__ out) {
  long long idx = (long long)blockIdx.x * blockDim.x + threadIdx.x;
  long long total = (long long)TOKENS * OUT_F;
  if (idx >= total) return;
  int t = (int)(idx / OUT_F);
  int o = (int)(idx % OUT_F);
  const float* xp = x + (size_t)t * IN_F;
  const int* wp = w + (size_t)o * IN_F;
  float acc = 0.f;
  for (int k = 0; k < IN_F; k += 4) {
    i32x4 wv = *(const i32x4*)(wp + k);
    f32x4 xv = *(const f32x4*)(xp + k);
    acc += xv[0] * (float)wv[0] + xv[1] * (float)wv[1]
         + xv[2] * (float)wv[2] + xv[3] * (float)wv[3];
  }
  out[idx] = acc * sc[o] + bs[o];
}

extern "C" void kernel_launch(void* const* d_in, const int* in_sizes, int n_in,
                              void* d_out, int out_size, void* d_ws, size_t ws_size,
                              hipStream_t stream) {
  const float* x  = (const float*)d_in[0];
  const int*   qw = (const int*)d_in[1];     // int8 values materialized as int32
  const float* sc = (const float*)d_in[2];
  const float* bs = (const float*)d_in[3];
  float* out = (float*)d_out;

  const size_t xqBytes = (size_t)TOKENS * IN_F;       // 32 MiB
  const size_t wqBytes = (size_t)OUT_F * IN_F;        // 43 MiB
  const size_t sxBytes = (size_t)TOKENS * sizeof(float);

  if (ws_size >= xqBytes + wqBytes + sxBytes) {
    signed char* xq = (signed char*)d_ws;
    signed char* wq = (signed char*)((char*)d_ws + xqBytes);
    float*       sx = (float*)((char*)d_ws + xqBytes + wqBytes);
    quant_x_kernel<<<TOKENS, 256, 0, stream>>>(x, xq, sx);
    cvt_w_kernel<<<2048, 256, 0, stream>>>(qw, wq, OUT_F * IN_F / 16);
    (void)hipFuncSetAttribute((const void*)gemm_i8_kernel,
                              hipFuncAttributeMaxDynamicSharedMemorySize,
                              LDS_TOTAL);
    gemm_i8_kernel<<<NWG, 512, LDS_TOTAL, stream>>>(xq, wq, sx, sc, bs, out);
  } else {
    long long total = (long long)TOKENS * OUT_F;
    int blocks = (int)((total + 255) / 256);
    gemm_naive_kernel<<<blocks, 256, 0, stream>>>(x, qw, sc, bs, out);
  }
}